// Round 6
// baseline (271.429 us; speedup 1.0000x reference)
//
#include <hip/hip_runtime.h>
#include <hip/hip_bf16.h>
#include <math.h>

#define B_TOTAL 16384
#define D 64
#define L_U 50
#define N_F 32
#define L_I 50
#define RSTRIDE 66   // row stride in floats (264 B). 4 tiles*50*66*4 = 52800 B ->
                     // LDS block 53248 B -> 3 blocks/CU (12 waves). Bank spread:
                     // dot b128 quads start (2*rl+4j)%32 (even, 8 dw/bank = min);
                     // weighted b32 bank (2l+lane)%32 = 2-way (free).

// ---------------------------------------------------------------------------
// Setup: u[0..63]=W1@W3, u[64..]=W2@W3, u[128..]=W4@W6, u[192..]=W5@W6,
//        u[256..]=W7@W9, u[320..]=W8@W9
// ---------------------------------------------------------------------------
__global__ void graphrec_setup(const float* __restrict__ W1, const float* __restrict__ W2,
                               const float* __restrict__ W3, const float* __restrict__ W4,
                               const float* __restrict__ W5, const float* __restrict__ W6,
                               const float* __restrict__ W7, const float* __restrict__ W8,
                               const float* __restrict__ W9, float* __restrict__ u) {
    int t = threadIdx.x;           // 0..383
    int w = t >> 6;                // which of 6 vectors
    int d = t & 63;
    const float* Wm;
    const float* Wv;
    switch (w) {
        case 0: Wm = W1; Wv = W3; break;
        case 1: Wm = W2; Wv = W3; break;
        case 2: Wm = W4; Wv = W6; break;
        case 3: Wm = W5; Wv = W6; break;
        case 4: Wm = W7; Wv = W9; break;
        default: Wm = W8; Wv = W9; break;
    }
    float s = 0.f;
    #pragma unroll
    for (int j = 0; j < D; ++j) s = fmaf(Wm[d * D + j], Wv[j], s);
    u[w * D + d] = s;
}

// ---------------------------------------------------------------------------
// Wave-wide reductions via DPP (VALU only, no LDS pipe). row_shr 1/2/4/8,
// row_bcast15 (rows 1,3), row_bcast31 (rows 2,3); lane 63 holds the result.
// ---------------------------------------------------------------------------
__device__ __forceinline__ float wred_sum(float x) {
    float t;
    #define STEP_ADD(ctrl, rmask)                                                        \
        t = __int_as_float(__builtin_amdgcn_update_dpp(0, __float_as_int(x),             \
                                                       ctrl, rmask, 0xf, false));        \
        x = x + t;
    STEP_ADD(0x111, 0xf)   // row_shr:1
    STEP_ADD(0x112, 0xf)   // row_shr:2
    STEP_ADD(0x114, 0xf)   // row_shr:4
    STEP_ADD(0x118, 0xf)   // row_shr:8
    STEP_ADD(0x142, 0xa)   // row_bcast:15 -> rows 1,3
    STEP_ADD(0x143, 0xc)   // row_bcast:31 -> rows 2,3
    #undef STEP_ADD
    return __int_as_float(__builtin_amdgcn_readlane(__float_as_int(x), 63));
}
__device__ __forceinline__ float wred_max(float x) {
    const int NEG_INF = 0xFF800000;
    float t;
    #define STEP_MAX(ctrl, rmask)                                                        \
        t = __int_as_float(__builtin_amdgcn_update_dpp(NEG_INF, __float_as_int(x),       \
                                                       ctrl, rmask, 0xf, false));        \
        x = fmaxf(x, t);
    STEP_MAX(0x111, 0xf)
    STEP_MAX(0x112, 0xf)
    STEP_MAX(0x114, 0xf)
    STEP_MAX(0x118, 0xf)
    STEP_MAX(0x142, 0xa)
    STEP_MAX(0x143, 0xc)
    #undef STEP_MAX
    return __int_as_float(__builtin_amdgcn_readlane(__float_as_int(x), 63));
}

// ---------------------------------------------------------------------------
// Two-pass attention through a wave-private stride-66 LDS tile.
//   cq     : wave-uniform query score term  q.(Wq@Wa)
//   table  : embedding table for neighbor gathers
//   u2g/wag: global ptrs to (Wk@Wa)[64] / Wa[64] as float4 — uniform index, so
//            these lower to scalar (SMEM) loads: zero LDS-pipe cost
//   idxreg : lane l (< L) holds neighbor index for slot l
//   r      : lane l (< L) holds rating for slot l
// ---------------------------------------------------------------------------
template <int L, bool HAS_R>
__device__ __forceinline__ float attn3(float cq, const float* __restrict__ table,
                                       const float4* __restrict__ u2g,
                                       const float4* __restrict__ wag,
                                       int idxreg, float r, int lane, float* tile) {
    // Previous phase's ds_reads of this tile must drain before DMA overwrites.
    asm volatile("s_waitcnt lgkmcnt(0)" ::: "memory");

    // ---- stage: one row (256 B) per 4 B-wide global_load_lds; uniform index
    //      via readlane -> scalar address math on the SALU.
    #pragma unroll
    for (int l = 0; l < L; ++l) {
        int idx = __builtin_amdgcn_readlane(idxreg, l);
        const float* gp = table + (size_t)(unsigned)idx * D + lane;
        __builtin_amdgcn_global_load_lds(
            (const __attribute__((address_space(1))) void*)gp,
            (__attribute__((address_space(3))) void*)(tile + l * RSTRIDE),
            4, 0, 0);                                    // lands at base+lane*4
    }
    asm volatile("s_waitcnt vmcnt(0)" ::: "memory");

    // ---- dot phase: lane = neighbor; uniform chunk j
    const int rl = (lane < L) ? lane : (L - 1);          // tail lanes: broadcast row
    const float* row = tile + rl * RSTRIDE;
    float dotU = 0.f, dotW = 0.f;
    #pragma unroll
    for (int j = 0; j < D / 4; ++j) {
        float4 n = *(const float4*)(row + 4 * j);        // ds_read_b128
        float4 uu = u2g[j];                              // scalar s_load
        dotU = fmaf(n.x, uu.x, fmaf(n.y, uu.y, fmaf(n.z, uu.z, fmaf(n.w, uu.w, dotU))));
        if (HAS_R) {
            float4 ww = wag[j];                          // scalar s_load
            dotW = fmaf(n.x, ww.x, fmaf(n.y, ww.y, fmaf(n.z, ww.z, fmaf(n.w, ww.w, dotW))));
        }
    }
    float sc = cq + dotU;
    if (HAS_R) sc = fmaf(r, dotW, sc);
    sc = (lane < L) ? sc : -1e30f;

    // ---- softmax across lanes: DPP reductions + one exp
    float m = wred_max(sc);
    float e = __expf(sc - m);
    float s = wred_sum(e);
    float w = e * (1.0f / s);

    // ---- weighted sum: lane = dim; bank (2l+lane)%32 -> 2-way, free
    float acc = 0.f;
    #pragma unroll
    for (int l = 0; l < L; ++l) {
        float wl = __int_as_float(__builtin_amdgcn_readlane(__float_as_int(w), l));
        acc = fmaf(wl, tile[l * RSTRIDE + lane], acc);
    }
    return acc;
}

__global__ __launch_bounds__(256) void graphrec_fwd(
        const int* __restrict__ user_ids, const int* __restrict__ item_ids,
        const int* __restrict__ uh_items, const float* __restrict__ uh_rat,
        const int* __restrict__ ufriends,
        const int* __restrict__ ih_users, const float* __restrict__ ih_rat,
        const float* __restrict__ eu, const float* __restrict__ ei,
        const float* __restrict__ W3, const float* __restrict__ W6,
        const float* __restrict__ W9,
        const float* __restrict__ fc1w, const float* __restrict__ fc1b,
        const float* __restrict__ fc2w, const float* __restrict__ fc2b,
        const float* __restrict__ u, float* __restrict__ out) {
    // 4 wave tiles, 50 rows x 66 floats = 52800 B -> block 53248 -> 3 blocks/CU.
    __shared__ __align__(16) float smem[4 * L_U * RSTRIDE];
    const int lane = threadIdx.x & 63;
    const int wv = threadIdx.x >> 6;
    const int b = blockIdx.x * 4 + wv;
    float* tile = smem + wv * (L_U * RSTRIDE);

    // Per-lane neighbor metadata (lane l holds slot l).
    int idxA = 0, idxB = 0, idxC = 0;
    float rA = 0.f, rC = 0.f;
    if (lane < L_U) {
        idxA = uh_items[b * L_U + lane];
        rA   = uh_rat[b * L_U + lane];
        idxC = ih_users[b * L_I + lane];
        rC   = ih_rat[b * L_I + lane];
    }
    if (lane < N_F) idxB = ufriends[b * N_F + lane];

    const int uid = user_ids[b];
    const int iid = item_ids[b];
    const float qu = eu[(size_t)uid * D + lane];
    const float qi = ei[(size_t)iid * D + lane];

    // cq = q . (Wq@Wa) for each attention (DPP reduce -> uniform)
    const float cqa = wred_sum(qu * u[lane]);
    const float cqb = wred_sum(qu * u[128 + lane]);
    const float cqc = wred_sum(qi * u[256 + lane]);

    const float accA = attn3<L_U, true >(cqa, ei, (const float4*)(u + 64),
                                         (const float4*)W3, idxA, rA, lane, tile);
    const float accB = attn3<N_F, false>(cqb, eu, (const float4*)(u + 192),
                                         (const float4*)W6, idxB, 0.f, lane, tile);
    const float accC = attn3<L_I, true >(cqc, eu, (const float4*)(u + 320),
                                         (const float4*)W9, idxC, rC, lane, tile);

    const float uf  = qu + accA + accB;   // user_emb_final[lane]
    const float itf = qi + accC;          // item_emb_final[lane]

    // MLP: h_j = relu(fc1b[j] + sum_k c_k fc1w[k*64+j]); c_k via readlane (VALU),
    // fc1w reads are coalesced 256 B, L1-hot.
    float h = fc1b[lane];
    #pragma unroll
    for (int k = 0; k < D; ++k) {
        float c = __int_as_float(__builtin_amdgcn_readlane(__float_as_int(uf), k));
        h = fmaf(c, fc1w[k * D + lane], h);
    }
    #pragma unroll
    for (int k = 0; k < D; ++k) {
        float c = __int_as_float(__builtin_amdgcn_readlane(__float_as_int(itf), k));
        h = fmaf(c, fc1w[(D + k) * D + lane], h);
    }
    h = fmaxf(h, 0.f);
    float o = wred_sum(h * fc2w[lane]);
    if (lane == 0) out[b] = o + fc2b[0];
}

extern "C" void kernel_launch(void* const* d_in, const int* in_sizes, int n_in,
                              void* d_out, int out_size, void* d_ws, size_t ws_size,
                              hipStream_t stream) {
    const int*   user_ids = (const int*)d_in[0];
    const int*   item_ids = (const int*)d_in[1];
    const int*   uh_items = (const int*)d_in[2];
    const float* uh_rat   = (const float*)d_in[3];
    const int*   ufriends = (const int*)d_in[4];
    const int*   ih_users = (const int*)d_in[5];
    const float* ih_rat   = (const float*)d_in[6];
    const float* eu       = (const float*)d_in[7];
    const float* ei       = (const float*)d_in[8];
    const float* W1 = (const float*)d_in[9];
    const float* W2 = (const float*)d_in[10];
    const float* W3 = (const float*)d_in[11];
    const float* W4 = (const float*)d_in[12];
    const float* W5 = (const float*)d_in[13];
    const float* W6 = (const float*)d_in[14];
    const float* W7 = (const float*)d_in[15];
    const float* W8 = (const float*)d_in[16];
    const float* W9 = (const float*)d_in[17];
    const float* fc1w = (const float*)d_in[18];
    const float* fc1b = (const float*)d_in[19];
    const float* fc2w = (const float*)d_in[20];
    const float* fc2b = (const float*)d_in[21];
    float* out = (float*)d_out;
    float* u   = (float*)d_ws;   // 6 * 64 floats = 1536 B

    graphrec_setup<<<1, 384, 0, stream>>>(W1, W2, W3, W4, W5, W6, W7, W8, W9, u);
    graphrec_fwd<<<B_TOTAL / 4, 256, 0, stream>>>(
        user_ids, item_ids, uh_items, uh_rat, ufriends, ih_users, ih_rat,
        eu, ei, W3, W6, W9, fc1w, fc1b, fc2w, fc2b, u, out);
}

// Round 8
// 210.019 us; speedup vs baseline: 1.2924x; 1.2924x over previous
//
#include <hip/hip_runtime.h>
#include <hip/hip_bf16.h>
#include <math.h>

#define B_TOTAL 16384
#define D 64
#define L_U 50
#define N_F 32
#define L_I 50
// Half-pad tile layout: row l at float offset 64*l + 4*(l>>1) (4-float pad per
// row pair). Non-overlapping (gap >= 64), rows 16B-aligned -> true ds_read_b128.
// Start bank 4*(l>>1)%32 -> 8 classes, ~6-8 rows each: dot-phase ~6-8 dw/bank
// (ideal 6.25); weighted phase 2-way (free). TILE_FL = ROWOFF(49)+64 = 3296;
// 4 tiles = 52736 B (exactly 103*512) -> 3 blocks/CU (12 waves).
#define ROWOFF(l) (((l) << 6) + ((((l) >> 1)) << 2))
#define TILE_FL 3296

// ---------------------------------------------------------------------------
// Setup: u[0..63]=W1@W3, u[64..]=W2@W3, u[128..]=W4@W6, u[192..]=W5@W6,
//        u[256..]=W7@W9, u[320..]=W8@W9
// ---------------------------------------------------------------------------
__global__ void graphrec_setup(const float* __restrict__ W1, const float* __restrict__ W2,
                               const float* __restrict__ W3, const float* __restrict__ W4,
                               const float* __restrict__ W5, const float* __restrict__ W6,
                               const float* __restrict__ W7, const float* __restrict__ W8,
                               const float* __restrict__ W9, float* __restrict__ u) {
    int t = threadIdx.x;           // 0..383
    int w = t >> 6;                // which of 6 vectors
    int d = t & 63;
    const float* Wm;
    const float* Wv;
    switch (w) {
        case 0: Wm = W1; Wv = W3; break;
        case 1: Wm = W2; Wv = W3; break;
        case 2: Wm = W4; Wv = W6; break;
        case 3: Wm = W5; Wv = W6; break;
        case 4: Wm = W7; Wv = W9; break;
        default: Wm = W8; Wv = W9; break;
    }
    float s = 0.f;
    #pragma unroll
    for (int j = 0; j < D; ++j) s = fmaf(Wm[d * D + j], Wv[j], s);
    u[w * D + d] = s;
}

// ---------------------------------------------------------------------------
// Wave-wide reductions via DPP (VALU only, no LDS pipe). row_shr 1/2/4/8,
// row_bcast15 (rows 1,3), row_bcast31 (rows 2,3); lane 63 holds the result.
// ---------------------------------------------------------------------------
__device__ __forceinline__ float wred_sum(float x) {
    float t;
    #define STEP_ADD(ctrl, rmask)                                                        \
        t = __int_as_float(__builtin_amdgcn_update_dpp(0, __float_as_int(x),             \
                                                       ctrl, rmask, 0xf, false));        \
        x = x + t;
    STEP_ADD(0x111, 0xf)   // row_shr:1
    STEP_ADD(0x112, 0xf)   // row_shr:2
    STEP_ADD(0x114, 0xf)   // row_shr:4
    STEP_ADD(0x118, 0xf)   // row_shr:8
    STEP_ADD(0x142, 0xa)   // row_bcast:15 -> rows 1,3
    STEP_ADD(0x143, 0xc)   // row_bcast:31 -> rows 2,3
    #undef STEP_ADD
    return __int_as_float(__builtin_amdgcn_readlane(__float_as_int(x), 63));
}
__device__ __forceinline__ float wred_max(float x) {
    const int NEG_INF = 0xFF800000;
    float t;
    #define STEP_MAX(ctrl, rmask)                                                        \
        t = __int_as_float(__builtin_amdgcn_update_dpp(NEG_INF, __float_as_int(x),       \
                                                       ctrl, rmask, 0xf, false));        \
        x = fmaxf(x, t);
    STEP_MAX(0x111, 0xf)
    STEP_MAX(0x112, 0xf)
    STEP_MAX(0x114, 0xf)
    STEP_MAX(0x118, 0xf)
    STEP_MAX(0x142, 0xa)
    STEP_MAX(0x143, 0xc)
    #undef STEP_MAX
    return __int_as_float(__builtin_amdgcn_readlane(__float_as_int(x), 63));
}

// ---------------------------------------------------------------------------
// Two-pass attention through a wave-private half-pad LDS tile.
//   cq     : wave-uniform query score term  q.(Wq@Wa)
//   table  : embedding table for neighbor gathers
//   u2g/wag: global ptrs to (Wk@Wa)[64] / Wa[64] as float4 — uniform index, so
//            these lower to scalar (SMEM) loads: zero LDS-pipe cost
//   idxreg : lane l (< L) holds neighbor index for slot l
//   r      : lane l (< L) holds rating for slot l
// ---------------------------------------------------------------------------
template <int L, bool HAS_R>
__device__ __forceinline__ float attn3(float cq, const float* __restrict__ table,
                                       const float4* __restrict__ u2g,
                                       const float4* __restrict__ wag,
                                       int idxreg, float r, int lane, float* tile) {
    // Previous phase's ds_reads of this tile must drain before DMA overwrites.
    asm volatile("s_waitcnt lgkmcnt(0)" ::: "memory");

    // ---- stage: one row (256 B) per 4 B-wide global_load_lds; uniform index
    //      via readlane -> scalar address math on the SALU.
    #pragma unroll
    for (int l = 0; l < L; ++l) {
        int idx = __builtin_amdgcn_readlane(idxreg, l);
        const float* gp = table + (size_t)(unsigned)idx * D + lane;
        __builtin_amdgcn_global_load_lds(
            (const __attribute__((address_space(1))) void*)gp,
            (__attribute__((address_space(3))) void*)(tile + ROWOFF(l)),
            4, 0, 0);                                    // lands at base+lane*4
    }
    asm volatile("s_waitcnt vmcnt(0)" ::: "memory");

    // ---- dot phase: lane = neighbor; uniform chunk j, 16B-aligned b128 reads
    const int rl = (lane < L) ? lane : (L - 1);          // tail lanes: broadcast row
    const float* row = tile + ROWOFF(rl);
    float dotU = 0.f, dotW = 0.f;
    #pragma unroll
    for (int j = 0; j < D / 4; ++j) {
        float4 n = *(const float4*)(row + 4 * j);        // ds_read_b128
        float4 uu = u2g[j];                              // scalar s_load
        dotU = fmaf(n.x, uu.x, fmaf(n.y, uu.y, fmaf(n.z, uu.z, fmaf(n.w, uu.w, dotU))));
        if (HAS_R) {
            float4 ww = wag[j];                          // scalar s_load
            dotW = fmaf(n.x, ww.x, fmaf(n.y, ww.y, fmaf(n.z, ww.z, fmaf(n.w, ww.w, dotW))));
        }
    }
    float sc = cq + dotU;
    if (HAS_R) sc = fmaf(r, dotW, sc);
    sc = (lane < L) ? sc : -1e30f;

    // ---- softmax across lanes: DPP reductions + one exp
    float m = wred_max(sc);
    float e = __expf(sc - m);
    float s = wred_sum(e);
    float w = e * (1.0f / s);

    // ---- weighted sum: lane = dim; bank (4*(l>>1)+lane)%32 -> 2-way, free
    float acc = 0.f;
    #pragma unroll
    for (int l = 0; l < L; ++l) {
        float wl = __int_as_float(__builtin_amdgcn_readlane(__float_as_int(w), l));
        acc = fmaf(wl, tile[ROWOFF(l) + lane], acc);
    }
    return acc;
}

__global__ __launch_bounds__(256) void graphrec_fwd(
        const int* __restrict__ user_ids, const int* __restrict__ item_ids,
        const int* __restrict__ uh_items, const float* __restrict__ uh_rat,
        const int* __restrict__ ufriends,
        const int* __restrict__ ih_users, const float* __restrict__ ih_rat,
        const float* __restrict__ eu, const float* __restrict__ ei,
        const float* __restrict__ W3, const float* __restrict__ W6,
        const float* __restrict__ W9,
        const float* __restrict__ fc1w, const float* __restrict__ fc1b,
        const float* __restrict__ fc2w, const float* __restrict__ fc2b,
        const float* __restrict__ u, float* __restrict__ out) {
    // 4 half-pad wave tiles = 52736 B -> 3 blocks/CU. No barriers.
    __shared__ __align__(16) float smem[4 * TILE_FL];
    const int lane = threadIdx.x & 63;
    const int wv = threadIdx.x >> 6;
    const int b = blockIdx.x * 4 + wv;
    float* tile = smem + wv * TILE_FL;

    // Per-lane neighbor metadata (lane l holds slot l).
    int idxA = 0, idxB = 0, idxC = 0;
    float rA = 0.f, rC = 0.f;
    if (lane < L_U) {
        idxA = uh_items[b * L_U + lane];
        rA   = uh_rat[b * L_U + lane];
        idxC = ih_users[b * L_I + lane];
        rC   = ih_rat[b * L_I + lane];
    }
    if (lane < N_F) idxB = ufriends[b * N_F + lane];

    const int uid = user_ids[b];
    const int iid = item_ids[b];
    const float qu = eu[(size_t)uid * D + lane];
    const float qi = ei[(size_t)iid * D + lane];

    // cq = q . (Wq@Wa) for each attention (DPP reduce -> uniform)
    const float cqa = wred_sum(qu * u[lane]);
    const float cqb = wred_sum(qu * u[128 + lane]);
    const float cqc = wred_sum(qi * u[256 + lane]);

    const float accA = attn3<L_U, true >(cqa, ei, (const float4*)(u + 64),
                                         (const float4*)W3, idxA, rA, lane, tile);
    const float accB = attn3<N_F, false>(cqb, eu, (const float4*)(u + 192),
                                         (const float4*)W6, idxB, 0.f, lane, tile);
    const float accC = attn3<L_I, true >(cqc, eu, (const float4*)(u + 320),
                                         (const float4*)W9, idxC, rC, lane, tile);

    const float uf  = qu + accA + accB;   // user_emb_final[lane]
    const float itf = qi + accC;          // item_emb_final[lane]

    // MLP: h_j = relu(fc1b[j] + sum_k c_k fc1w[k*64+j]); c_k via readlane (VALU),
    // fc1w reads are coalesced 256 B, L1-hot.
    float h = fc1b[lane];
    #pragma unroll
    for (int k = 0; k < D; ++k) {
        float c = __int_as_float(__builtin_amdgcn_readlane(__float_as_int(uf), k));
        h = fmaf(c, fc1w[k * D + lane], h);
    }
    #pragma unroll
    for (int k = 0; k < D; ++k) {
        float c = __int_as_float(__builtin_amdgcn_readlane(__float_as_int(itf), k));
        h = fmaf(c, fc1w[(D + k) * D + lane], h);
    }
    h = fmaxf(h, 0.f);
    float o = wred_sum(h * fc2w[lane]);
    if (lane == 0) out[b] = o + fc2b[0];
}

extern "C" void kernel_launch(void* const* d_in, const int* in_sizes, int n_in,
                              void* d_out, int out_size, void* d_ws, size_t ws_size,
                              hipStream_t stream) {
    const int*   user_ids = (const int*)d_in[0];
    const int*   item_ids = (const int*)d_in[1];
    const int*   uh_items = (const int*)d_in[2];
    const float* uh_rat   = (const float*)d_in[3];
    const int*   ufriends = (const int*)d_in[4];
    const int*   ih_users = (const int*)d_in[5];
    const float* ih_rat   = (const float*)d_in[6];
    const float* eu       = (const float*)d_in[7];
    const float* ei       = (const float*)d_in[8];
    const float* W1 = (const float*)d_in[9];
    const float* W2 = (const float*)d_in[10];
    const float* W3 = (const float*)d_in[11];
    const float* W4 = (const float*)d_in[12];
    const float* W5 = (const float*)d_in[13];
    const float* W6 = (const float*)d_in[14];
    const float* W7 = (const float*)d_in[15];
    const float* W8 = (const float*)d_in[16];
    const float* W9 = (const float*)d_in[17];
    const float* fc1w = (const float*)d_in[18];
    const float* fc1b = (const float*)d_in[19];
    const float* fc2w = (const float*)d_in[20];
    const float* fc2b = (const float*)d_in[21];
    float* out = (float*)d_out;
    float* u   = (float*)d_ws;   // 6 * 64 floats = 1536 B

    graphrec_setup<<<1, 384, 0, stream>>>(W1, W2, W3, W4, W5, W6, W7, W8, W9, u);
    graphrec_fwd<<<B_TOTAL / 4, 256, 0, stream>>>(
        user_ids, item_ids, uh_items, uh_rat, ufriends, ih_users, ih_rat,
        eu, ei, W3, W6, W9, fc1w, fc1b, fc2w, fc2b, u, out);
}

// Round 9
// 209.569 us; speedup vs baseline: 1.2952x; 1.0021x over previous
//
#include <hip/hip_runtime.h>
#include <hip/hip_bf16.h>
#include <math.h>

#define B_TOTAL 16384
#define D 64
#define L_U 50
#define N_F 32
#define L_I 50
// Pad-per-4-rows layout: row l at float offset 64*l + 4*(l>>2). Rows within a
// 4-row group are CONTIGUOUS (1 KiB) -> one 16B-wide global_load_lds stages 4
// rows. Rows 16B-aligned -> true ds_read_b128. Dot phase (lane=row, uniform
// chunk j): bank window ((l>>2)+j)&7 -> <=8 addresses/bank = b128 minimum ->
// conflict-free. Weighted phase: 2 dw/bank -> free.
// TILE_FL = ROWOFF(49)+64 = 3248; 4 tiles = 51968 B -> 3 blocks/CU (12 waves).
#define ROWOFF(l) (((l) << 6) + ((((l) >> 2)) << 2))
#define TILE_FL 3248

// ---------------------------------------------------------------------------
// Setup: u[0..63]=W1@W3, u[64..]=W2@W3, u[128..]=W4@W6, u[192..]=W5@W6,
//        u[256..]=W7@W9, u[320..]=W8@W9
// ---------------------------------------------------------------------------
__global__ void graphrec_setup(const float* __restrict__ W1, const float* __restrict__ W2,
                               const float* __restrict__ W3, const float* __restrict__ W4,
                               const float* __restrict__ W5, const float* __restrict__ W6,
                               const float* __restrict__ W7, const float* __restrict__ W8,
                               const float* __restrict__ W9, float* __restrict__ u) {
    int t = threadIdx.x;           // 0..383
    int w = t >> 6;                // which of 6 vectors
    int d = t & 63;
    const float* Wm;
    const float* Wv;
    switch (w) {
        case 0: Wm = W1; Wv = W3; break;
        case 1: Wm = W2; Wv = W3; break;
        case 2: Wm = W4; Wv = W6; break;
        case 3: Wm = W5; Wv = W6; break;
        case 4: Wm = W7; Wv = W9; break;
        default: Wm = W8; Wv = W9; break;
    }
    float s = 0.f;
    #pragma unroll
    for (int j = 0; j < D; ++j) s = fmaf(Wm[d * D + j], Wv[j], s);
    u[w * D + d] = s;
}

// ---------------------------------------------------------------------------
// Wave-wide reductions via DPP (VALU only, no LDS pipe). row_shr 1/2/4/8,
// row_bcast15 (rows 1,3), row_bcast31 (rows 2,3); lane 63 holds the result.
// ---------------------------------------------------------------------------
__device__ __forceinline__ float wred_sum(float x) {
    float t;
    #define STEP_ADD(ctrl, rmask)                                                        \
        t = __int_as_float(__builtin_amdgcn_update_dpp(0, __float_as_int(x),             \
                                                       ctrl, rmask, 0xf, false));        \
        x = x + t;
    STEP_ADD(0x111, 0xf)   // row_shr:1
    STEP_ADD(0x112, 0xf)   // row_shr:2
    STEP_ADD(0x114, 0xf)   // row_shr:4
    STEP_ADD(0x118, 0xf)   // row_shr:8
    STEP_ADD(0x142, 0xa)   // row_bcast:15 -> rows 1,3
    STEP_ADD(0x143, 0xc)   // row_bcast:31 -> rows 2,3
    #undef STEP_ADD
    return __int_as_float(__builtin_amdgcn_readlane(__float_as_int(x), 63));
}
__device__ __forceinline__ float wred_max(float x) {
    const int NEG_INF = 0xFF800000;
    float t;
    #define STEP_MAX(ctrl, rmask)                                                        \
        t = __int_as_float(__builtin_amdgcn_update_dpp(NEG_INF, __float_as_int(x),       \
                                                       ctrl, rmask, 0xf, false));        \
        x = fmaxf(x, t);
    STEP_MAX(0x111, 0xf)
    STEP_MAX(0x112, 0xf)
    STEP_MAX(0x114, 0xf)
    STEP_MAX(0x118, 0xf)
    STEP_MAX(0x142, 0xa)
    STEP_MAX(0x143, 0xc)
    #undef STEP_MAX
    return __int_as_float(__builtin_amdgcn_readlane(__float_as_int(x), 63));
}

// ---------------------------------------------------------------------------
// Two-pass attention through a wave-private pad-per-4 LDS tile.
//   cq     : wave-uniform query score term  q.(Wq@Wa)
//   table  : embedding table for neighbor gathers
//   u2g/wag: global ptrs to (Wk@Wa)[64] / Wa[64] as float4 — uniform index, so
//            these lower to scalar (SMEM) loads: zero LDS-pipe cost
//   idxreg : lane l (< L) holds neighbor index for slot l
//   r      : lane l (< L) holds rating for slot l
// ---------------------------------------------------------------------------
template <int L, bool HAS_R>
__device__ __forceinline__ float attn4(float cq, const float* __restrict__ table,
                                       const float4* __restrict__ u2g,
                                       const float4* __restrict__ wag,
                                       int idxreg, float r, int lane, float* tile) {
    // Previous phase's ds_reads of this tile must drain before DMA overwrites.
    asm volatile("s_waitcnt lgkmcnt(0)" ::: "memory");

    // ---- stage: 4 rows (1 KiB contiguous) per 16B-wide global_load_lds.
    //      Row index for this lane's slot via ds_bpermute of the lane-resident
    //      index vector; voffset = idx*256 + chunk*16 (32-bit, tables < 26 MB).
    const int sub4 = (lane >> 4) << 2;            // bpermute byte addr: sub*4
    const int chunk16 = (lane & 15) << 4;         // byte offset within 1 KiB
    #pragma unroll
    for (int g = 0; g < L / 4; ++g) {
        int rowidx = __builtin_amdgcn_ds_bpermute(sub4 + 16 * g, idxreg); // idx[4g+sub]
        unsigned vo = ((unsigned)rowidx << 8) + (unsigned)chunk16;
        const char* gp = (const char*)table + vo;
        __builtin_amdgcn_global_load_lds(
            (const __attribute__((address_space(1))) void*)gp,
            (__attribute__((address_space(3))) void*)(tile + ROWOFF(4 * g)),
            16, 0, 0);                            // lane lands at base + lane*16
    }
    if (L & 3) {                                  // tail rows (L=50: rows 48,49)
        #pragma unroll
        for (int l = L & ~3; l < L; ++l) {
            int idx = __builtin_amdgcn_readlane(idxreg, l);
            const float* gp = table + (size_t)(unsigned)idx * D + lane;
            __builtin_amdgcn_global_load_lds(
                (const __attribute__((address_space(1))) void*)gp,
                (__attribute__((address_space(3))) void*)(tile + ROWOFF(l)),
                4, 0, 0);
        }
    }
    asm volatile("s_waitcnt vmcnt(0)" ::: "memory");

    // ---- dot phase: lane = neighbor; uniform chunk j, 16B-aligned b128 reads
    const int rl = (lane < L) ? lane : (L - 1);          // tail lanes: broadcast row
    const float* row = tile + ROWOFF(rl);
    float dotU = 0.f, dotW = 0.f;
    #pragma unroll
    for (int j = 0; j < D / 4; ++j) {
        float4 n = *(const float4*)(row + 4 * j);        // ds_read_b128
        float4 uu = u2g[j];                              // scalar s_load
        dotU = fmaf(n.x, uu.x, fmaf(n.y, uu.y, fmaf(n.z, uu.z, fmaf(n.w, uu.w, dotU))));
        if (HAS_R) {
            float4 ww = wag[j];                          // scalar s_load
            dotW = fmaf(n.x, ww.x, fmaf(n.y, ww.y, fmaf(n.z, ww.z, fmaf(n.w, ww.w, dotW))));
        }
    }
    float sc = cq + dotU;
    if (HAS_R) sc = fmaf(r, dotW, sc);
    sc = (lane < L) ? sc : -1e30f;

    // ---- softmax across lanes: DPP reductions + one exp
    float m = wred_max(sc);
    float e = __expf(sc - m);
    float s = wred_sum(e);
    float w = e * (1.0f / s);

    // ---- weighted sum: lane = dim; bank (4*(l>>2)+lane)%32 -> 2-way, free
    float acc = 0.f;
    #pragma unroll
    for (int l = 0; l < L; ++l) {
        float wl = __int_as_float(__builtin_amdgcn_readlane(__float_as_int(w), l));
        acc = fmaf(wl, tile[ROWOFF(l) + lane], acc);
    }
    return acc;
}

__global__ __launch_bounds__(256) void graphrec_fwd(
        const int* __restrict__ user_ids, const int* __restrict__ item_ids,
        const int* __restrict__ uh_items, const float* __restrict__ uh_rat,
        const int* __restrict__ ufriends,
        const int* __restrict__ ih_users, const float* __restrict__ ih_rat,
        const float* __restrict__ eu, const float* __restrict__ ei,
        const float* __restrict__ W3, const float* __restrict__ W6,
        const float* __restrict__ W9,
        const float* __restrict__ fc1w, const float* __restrict__ fc1b,
        const float* __restrict__ fc2w, const float* __restrict__ fc2b,
        const float* __restrict__ u, float* __restrict__ out) {
    // 4 pad-per-4 wave tiles = 51968 B -> 3 blocks/CU. No barriers.
    __shared__ __align__(16) float smem[4 * TILE_FL];
    const int lane = threadIdx.x & 63;
    const int wv = threadIdx.x >> 6;
    const int b = blockIdx.x * 4 + wv;
    float* tile = smem + wv * TILE_FL;

    // Per-lane neighbor metadata (lane l holds slot l).
    int idxA = 0, idxB = 0, idxC = 0;
    float rA = 0.f, rC = 0.f;
    if (lane < L_U) {
        idxA = uh_items[b * L_U + lane];
        rA   = uh_rat[b * L_U + lane];
        idxC = ih_users[b * L_I + lane];
        rC   = ih_rat[b * L_I + lane];
    }
    if (lane < N_F) idxB = ufriends[b * N_F + lane];

    const int uid = user_ids[b];
    const int iid = item_ids[b];
    const float qu = eu[(size_t)uid * D + lane];
    const float qi = ei[(size_t)iid * D + lane];

    // cq = q . (Wq@Wa) for each attention (DPP reduce -> uniform)
    const float cqa = wred_sum(qu * u[lane]);
    const float cqb = wred_sum(qu * u[128 + lane]);
    const float cqc = wred_sum(qi * u[256 + lane]);

    const float accA = attn4<L_U, true >(cqa, ei, (const float4*)(u + 64),
                                         (const float4*)W3, idxA, rA, lane, tile);
    const float accB = attn4<N_F, false>(cqb, eu, (const float4*)(u + 192),
                                         (const float4*)W6, idxB, 0.f, lane, tile);
    const float accC = attn4<L_I, true >(cqc, eu, (const float4*)(u + 320),
                                         (const float4*)W9, idxC, rC, lane, tile);

    const float uf  = qu + accA + accB;   // user_emb_final[lane]
    const float itf = qi + accC;          // item_emb_final[lane]

    // MLP: h_j = relu(fc1b[j] + sum_k c_k fc1w[k*64+j]); c_k via readlane (VALU),
    // fc1w reads are coalesced 256 B, L1-hot.
    float h = fc1b[lane];
    #pragma unroll
    for (int k = 0; k < D; ++k) {
        float c = __int_as_float(__builtin_amdgcn_readlane(__float_as_int(uf), k));
        h = fmaf(c, fc1w[k * D + lane], h);
    }
    #pragma unroll
    for (int k = 0; k < D; ++k) {
        float c = __int_as_float(__builtin_amdgcn_readlane(__float_as_int(itf), k));
        h = fmaf(c, fc1w[(D + k) * D + lane], h);
    }
    h = fmaxf(h, 0.f);
    float o = wred_sum(h * fc2w[lane]);
    if (lane == 0) out[b] = o + fc2b[0];
}

extern "C" void kernel_launch(void* const* d_in, const int* in_sizes, int n_in,
                              void* d_out, int out_size, void* d_ws, size_t ws_size,
                              hipStream_t stream) {
    const int*   user_ids = (const int*)d_in[0];
    const int*   item_ids = (const int*)d_in[1];
    const int*   uh_items = (const int*)d_in[2];
    const float* uh_rat   = (const float*)d_in[3];
    const int*   ufriends = (const int*)d_in[4];
    const int*   ih_users = (const int*)d_in[5];
    const float* ih_rat   = (const float*)d_in[6];
    const float* eu       = (const float*)d_in[7];
    const float* ei       = (const float*)d_in[8];
    const float* W1 = (const float*)d_in[9];
    const float* W2 = (const float*)d_in[10];
    const float* W3 = (const float*)d_in[11];
    const float* W4 = (const float*)d_in[12];
    const float* W5 = (const float*)d_in[13];
    const float* W6 = (const float*)d_in[14];
    const float* W7 = (const float*)d_in[15];
    const float* W8 = (const float*)d_in[16];
    const float* W9 = (const float*)d_in[17];
    const float* fc1w = (const float*)d_in[18];
    const float* fc1b = (const float*)d_in[19];
    const float* fc2w = (const float*)d_in[20];
    const float* fc2b = (const float*)d_in[21];
    float* out = (float*)d_out;
    float* u   = (float*)d_ws;   // 6 * 64 floats = 1536 B

    graphrec_setup<<<1, 384, 0, stream>>>(W1, W2, W3, W4, W5, W6, W7, W8, W9, u);
    graphrec_fwd<<<B_TOTAL / 4, 256, 0, stream>>>(
        user_ids, item_ids, uh_items, uh_rat, ufriends, ih_users, ih_rat,
        eu, ei, W3, W6, W9, fc1w, fc1b, fc2w, fc2b, u, out);
}

// Round 10
// 205.093 us; speedup vs baseline: 1.3234x; 1.0218x over previous
//
#include <hip/hip_runtime.h>
#include <hip/hip_bf16.h>
#include <math.h>

#define B_TOTAL 16384
#define D 64
#define L_U 50
#define N_F 32
#define L_I 50
// Pad-per-4-rows layout: row l at float offset 64*l + 4*(l>>2). Rows within a
// 4-row group are contiguous (1 KiB); rows 16B-aligned -> true b128 LDS ops.
// TILE_FL = ROWOFF(49)+64 = 3248; 4 tiles -> LDS block 52224 B -> 3 blocks/CU.
#define ROWOFF(l) (((l) << 6) + ((((l) >> 2)) << 2))
#define TILE_FL 3248

// ---------------------------------------------------------------------------
// Setup: u[0..63]=W1@W3, u[64..]=W2@W3, u[128..]=W4@W6, u[192..]=W5@W6,
//        u[256..]=W7@W9, u[320..]=W8@W9
// ---------------------------------------------------------------------------
__global__ void graphrec_setup(const float* __restrict__ W1, const float* __restrict__ W2,
                               const float* __restrict__ W3, const float* __restrict__ W4,
                               const float* __restrict__ W5, const float* __restrict__ W6,
                               const float* __restrict__ W7, const float* __restrict__ W8,
                               const float* __restrict__ W9, float* __restrict__ u) {
    int t = threadIdx.x;           // 0..383
    int w = t >> 6;                // which of 6 vectors
    int d = t & 63;
    const float* Wm;
    const float* Wv;
    switch (w) {
        case 0: Wm = W1; Wv = W3; break;
        case 1: Wm = W2; Wv = W3; break;
        case 2: Wm = W4; Wv = W6; break;
        case 3: Wm = W5; Wv = W6; break;
        case 4: Wm = W7; Wv = W9; break;
        default: Wm = W8; Wv = W9; break;
    }
    float s = 0.f;
    #pragma unroll
    for (int j = 0; j < D; ++j) s = fmaf(Wm[d * D + j], Wv[j], s);
    u[w * D + d] = s;
}

// ---------------------------------------------------------------------------
// Wave-wide reductions via DPP (VALU only). row_shr 1/2/4/8, row_bcast15
// (rows 1,3), row_bcast31 (rows 2,3); lane 63 holds the result.
// ---------------------------------------------------------------------------
__device__ __forceinline__ float wred_sum(float x) {
    float t;
    #define STEP_ADD(ctrl, rmask)                                                        \
        t = __int_as_float(__builtin_amdgcn_update_dpp(0, __float_as_int(x),             \
                                                       ctrl, rmask, 0xf, false));        \
        x = x + t;
    STEP_ADD(0x111, 0xf)
    STEP_ADD(0x112, 0xf)
    STEP_ADD(0x114, 0xf)
    STEP_ADD(0x118, 0xf)
    STEP_ADD(0x142, 0xa)
    STEP_ADD(0x143, 0xc)
    #undef STEP_ADD
    return __int_as_float(__builtin_amdgcn_readlane(__float_as_int(x), 63));
}
__device__ __forceinline__ float wred_max(float x) {
    const int NEG_INF = 0xFF800000;
    float t;
    #define STEP_MAX(ctrl, rmask)                                                        \
        t = __int_as_float(__builtin_amdgcn_update_dpp(NEG_INF, __float_as_int(x),       \
                                                       ctrl, rmask, 0xf, false));        \
        x = fmaxf(x, t);
    STEP_MAX(0x111, 0xf)
    STEP_MAX(0x112, 0xf)
    STEP_MAX(0x114, 0xf)
    STEP_MAX(0x118, 0xf)
    STEP_MAX(0x142, 0xa)
    STEP_MAX(0x143, 0xc)
    #undef STEP_MAX
    return __int_as_float(__builtin_amdgcn_readlane(__float_as_int(x), 63));
}

// ---------------------------------------------------------------------------
// VGPR staging: lane (sub=lane>>4, c=lane&15) loads chunk c of row 4g+sub for
// each 4-row group g. Plain vector loads -> compiler emits fine-grained
// per-load s_waitcnt, so loads for attention n+1 issue before compute of n
// (inexpressible with global_load_lds, whose LDS-DMA forces vmcnt(0) drains).
// ---------------------------------------------------------------------------
template <int L>
__device__ __forceinline__ void stage_load(const float* __restrict__ table,
                                           int idxreg, int lane, float4* buf) {
    const int sub = lane >> 4;
    const int co = (lane & 15) << 2;                  // float offset of 16B chunk
    #pragma unroll
    for (int g = 0; g < (L + 3) / 4; ++g) {
        int l = 4 * g + sub;
        if (l > L - 1) l = L - 1;                     // tail: duplicate row L-1
        int ridx = __builtin_amdgcn_ds_bpermute(l << 2, idxreg);
        buf[g] = *(const float4*)(table + (size_t)(unsigned)ridx * D + co);
    }
}

template <int L>
__device__ __forceinline__ void stage_write(const float4* buf, int lane, float* tile) {
    const int sub = lane >> 4;
    const int co = (lane & 15) << 2;
    #pragma unroll
    for (int g = 0; g < (L + 3) / 4; ++g) {
        int l = 4 * g + sub;
        if (l > L - 1) l = L - 1;                     // duplicate write, same data
        *(float4*)(tile + (l << 6) + (g << 2) + co) = buf[g];   // ds_write_b128
    }
}

// ---------------------------------------------------------------------------
// Compute phase: dot (lane=row, b128), DPP softmax (1 exp), weighted sum
// (lane=dim, b32, 2-way banks). Coefficients u2g/wag via uniform scalar loads.
// ---------------------------------------------------------------------------
template <int L, bool HAS_R>
__device__ __forceinline__ float attn_compute(float cq,
                                              const float4* __restrict__ u2g,
                                              const float4* __restrict__ wag,
                                              float r, int lane, const float* tile) {
    const int rl = (lane < L) ? lane : (L - 1);
    const float* row = tile + ROWOFF(rl);
    float dotU = 0.f, dotW = 0.f;
    #pragma unroll
    for (int j = 0; j < D / 4; ++j) {
        float4 n = *(const float4*)(row + 4 * j);     // ds_read_b128
        float4 uu = u2g[j];                           // scalar s_load
        dotU = fmaf(n.x, uu.x, fmaf(n.y, uu.y, fmaf(n.z, uu.z, fmaf(n.w, uu.w, dotU))));
        if (HAS_R) {
            float4 ww = wag[j];                       // scalar s_load
            dotW = fmaf(n.x, ww.x, fmaf(n.y, ww.y, fmaf(n.z, ww.z, fmaf(n.w, ww.w, dotW))));
        }
    }
    float sc = cq + dotU;
    if (HAS_R) sc = fmaf(r, dotW, sc);
    sc = (lane < L) ? sc : -1e30f;

    float m = wred_max(sc);
    float e = __expf(sc - m);
    float s = wred_sum(e);
    float w = e * (1.0f / s);

    float acc = 0.f;
    #pragma unroll
    for (int l = 0; l < L; ++l) {
        float wl = __int_as_float(__builtin_amdgcn_readlane(__float_as_int(w), l));
        acc = fmaf(wl, tile[ROWOFF(l) + lane], acc);
    }
    return acc;
}

__global__ __launch_bounds__(256, 3) void graphrec_fwd(
        const int* __restrict__ user_ids, const int* __restrict__ item_ids,
        const int* __restrict__ uh_items, const float* __restrict__ uh_rat,
        const int* __restrict__ ufriends,
        const int* __restrict__ ih_users, const float* __restrict__ ih_rat,
        const float* __restrict__ eu, const float* __restrict__ ei,
        const float* __restrict__ W3, const float* __restrict__ W6,
        const float* __restrict__ W9,
        const float* __restrict__ fc1w, const float* __restrict__ fc1b,
        const float* __restrict__ fc2w, const float* __restrict__ fc2b,
        const float* __restrict__ u, float* __restrict__ out) {
    // 4 pad-per-4 wave tiles -> 52224 B block -> 3 blocks/CU. No barriers.
    __shared__ __align__(16) float smem[4 * TILE_FL];
    const int lane = threadIdx.x & 63;
    const int wv = threadIdx.x >> 6;
    const int b = blockIdx.x * 4 + wv;
    float* tile = smem + wv * TILE_FL;

    // Per-lane neighbor metadata (lane l holds slot l).
    int idxA = 0, idxB = 0, idxC = 0;
    float rA = 0.f, rC = 0.f;
    if (lane < L_U) {
        idxA = uh_items[b * L_U + lane];
        rA   = uh_rat[b * L_U + lane];
        idxC = ih_users[b * L_I + lane];
        rC   = ih_rat[b * L_I + lane];
    }
    if (lane < N_F) idxB = ufriends[b * N_F + lane];

    // Issue A and B gathers immediately (fly behind the prelude + A's write).
    float4 bufA[(L_U + 3) / 4];
    float4 bufB[(N_F + 3) / 4];
    stage_load<L_U>(ei, idxA, lane, bufA);
    stage_load<N_F>(eu, idxB, lane, bufB);

    const int uid = user_ids[b];
    const int iid = item_ids[b];
    const float qu = eu[(size_t)uid * D + lane];
    const float qi = ei[(size_t)iid * D + lane];

    // cq = q . (Wq@Wa) for each attention (DPP reduce -> uniform)
    const float cqa = wred_sum(qu * u[lane]);
    const float cqb = wred_sum(qu * u[128 + lane]);
    const float cqc = wred_sum(qi * u[256 + lane]);

    // ---- A: write tile, issue C, compute
    stage_write<L_U>(bufA, lane, tile);
    float4 bufC[(L_I + 3) / 4];
    stage_load<L_I>(eu, idxC, lane, bufC);            // flies during A/B compute
    const float accA = attn_compute<L_U, true >(cqa, (const float4*)(u + 64),
                                                (const float4*)W3, rA, lane, tile);

    // ---- B: tile free after A's weighted sum
    stage_write<N_F>(bufB, lane, tile);
    const float accB = attn_compute<N_F, false>(cqb, (const float4*)(u + 192),
                                                (const float4*)W6, 0.f, lane, tile);

    // ---- C
    stage_write<L_I>(bufC, lane, tile);
    const float accC = attn_compute<L_I, true >(cqc, (const float4*)(u + 320),
                                                (const float4*)W9, rC, lane, tile);

    const float uf  = qu + accA + accB;   // user_emb_final[lane]
    const float itf = qi + accC;          // item_emb_final[lane]

    // MLP: h_j = relu(fc1b[j] + sum_k c_k fc1w[k*64+j]); c_k via readlane,
    // fc1w reads coalesced 256 B, L1-hot.
    float h = fc1b[lane];
    #pragma unroll
    for (int k = 0; k < D; ++k) {
        float c = __int_as_float(__builtin_amdgcn_readlane(__float_as_int(uf), k));
        h = fmaf(c, fc1w[k * D + lane], h);
    }
    #pragma unroll
    for (int k = 0; k < D; ++k) {
        float c = __int_as_float(__builtin_amdgcn_readlane(__float_as_int(itf), k));
        h = fmaf(c, fc1w[(D + k) * D + lane], h);
    }
    h = fmaxf(h, 0.f);
    float o = wred_sum(h * fc2w[lane]);
    if (lane == 0) out[b] = o + fc2b[0];
}

extern "C" void kernel_launch(void* const* d_in, const int* in_sizes, int n_in,
                              void* d_out, int out_size, void* d_ws, size_t ws_size,
                              hipStream_t stream) {
    const int*   user_ids = (const int*)d_in[0];
    const int*   item_ids = (const int*)d_in[1];
    const int*   uh_items = (const int*)d_in[2];
    const float* uh_rat   = (const float*)d_in[3];
    const int*   ufriends = (const int*)d_in[4];
    const int*   ih_users = (const int*)d_in[5];
    const float* ih_rat   = (const float*)d_in[6];
    const float* eu       = (const float*)d_in[7];
    const float* ei       = (const float*)d_in[8];
    const float* W1 = (const float*)d_in[9];
    const float* W2 = (const float*)d_in[10];
    const float* W3 = (const float*)d_in[11];
    const float* W4 = (const float*)d_in[12];
    const float* W5 = (const float*)d_in[13];
    const float* W6 = (const float*)d_in[14];
    const float* W7 = (const float*)d_in[15];
    const float* W8 = (const float*)d_in[16];
    const float* W9 = (const float*)d_in[17];
    const float* fc1w = (const float*)d_in[18];
    const float* fc1b = (const float*)d_in[19];
    const float* fc2w = (const float*)d_in[20];
    const float* fc2b = (const float*)d_in[21];
    float* out = (float*)d_out;
    float* u   = (float*)d_ws;   // 6 * 64 floats = 1536 B

    graphrec_setup<<<1, 384, 0, stream>>>(W1, W2, W3, W4, W5, W6, W7, W8, W9, u);
    graphrec_fwd<<<B_TOTAL / 4, 256, 0, stream>>>(
        user_ids, item_ids, uh_items, uh_rat, ufriends, ih_users, ih_rat,
        eu, ei, W3, W6, W9, fc1w, fc1b, fc2w, fc2b, u, out);
}